// Round 6
// baseline (5396.686 us; speedup 1.0000x reference)
//
#include <hip/hip_runtime.h>
#include <math.h>

// Problem constants (B, T, D_IN, D_OUT) = (64, 1024, 512, 512)
#define BATCH   64
#define TSTEPS  1024
#define DIN     512
#define DH      512
#define MDIM    (BATCH * TSTEPS)

// ---- K2 geometry: 4 wgs x 256 thr (4 waves); wg = 16 batches; wave = 128 cols
//      (8 col-slices of 16): s0..s5 in registers (384 regs, V+A split),
//      s6 in LDS, s7 streamed from L2 (bulk, window-4).
//      H[16][512] fp16 double-buffered in LDS (XOR-swizzled) -> 1 barrier/step.
#define MB     16
#define SLICE_W 4096                 // 16 cols x 256 words per LDS Wr slice
#define HBUF_W  4096                 // 16 rows x 256 words per H buffer
#define K2_LDS_WORDS (4 * SLICE_W + 2 * HBUF_W)   // 24576 words
#define K2_LDS_BYTES (K2_LDS_WORDS * 4)           // 98304 B

typedef _Float16 f16x8 __attribute__((ext_vector_type(8)));
typedef float    f32x4 __attribute__((ext_vector_type(4)));

__device__ inline unsigned short f2h_bits(float x) {
    _Float16 h = (_Float16)x;
    return __builtin_bit_cast(unsigned short, h);
}
// fast tanh: 1 - 2/(exp2(2x*log2e)+1); saturates correctly incl. +-inf
__device__ inline float ftanh(float x) {
    float e = __builtin_amdgcn_exp2f(x * 2.88539008177792681472f);
    return 1.0f - 2.0f * __builtin_amdgcn_rcpf(e + 1.0f);
}
// word-index XOR swizzle (bits 2..4) keyed by row&7; preserves 4-word frags
__device__ inline int swz(int row, int off) { return off ^ ((row & 7) << 2); }

// ---------------------------------------------------------------------------
// K1a: convert x (fp32) -> Xh (fp16)
// ---------------------------------------------------------------------------
__global__ __launch_bounds__(256) void convert_x(const float* __restrict__ x,
                                                 _Float16* __restrict__ xh,
                                                 int nvec) {
    int i = blockIdx.x * blockDim.x + threadIdx.x;
    int stride = gridDim.x * blockDim.x;
    for (; i < nvec; i += stride) {
        const float4* p = (const float4*)x + 2 * (size_t)i;
        float4 a = p[0], b = p[1];
        f16x8 o = { (_Float16)a.x, (_Float16)a.y, (_Float16)a.z, (_Float16)a.w,
                    (_Float16)b.x, (_Float16)b.y, (_Float16)b.z, (_Float16)b.w };
        ((f16x8*)xh)[i] = o;
    }
}

// ---------------------------------------------------------------------------
// K1b: Out[n][k] = (fp16) In[k][n]   (512x512) — for W and Wr
// ---------------------------------------------------------------------------
__global__ __launch_bounds__(256) void transpose_w(const float* __restrict__ In,
                                                   _Float16* __restrict__ Out) {
    __shared__ float tile[64][65];
    const int t  = threadIdx.x;
    const int c  = t & 63;
    const int r0 = t >> 6;
    const int bn = blockIdx.x & 7;
    const int bk = blockIdx.x >> 3;
    const int k0 = bk * 64, n0 = bn * 64;
    #pragma unroll
    for (int i = 0; i < 16; ++i)
        tile[r0 + 4 * i][c] = In[(size_t)(k0 + r0 + 4 * i) * DH + n0 + c];
    __syncthreads();
    #pragma unroll
    for (int i = 0; i < 16; ++i)
        Out[(size_t)(n0 + r0 + 4 * i) * DIN + k0 + c] = (_Float16)tile[c][r0 + 4 * i];
}

// ---------------------------------------------------------------------------
// K1c: XWh = fp16( Xh @ Wt^T + bias )  via mfma_f32_16x16x32_f16 (validated)
// ---------------------------------------------------------------------------
__global__ __launch_bounds__(256) void gemm_xw_mfma(const _Float16* __restrict__ Xh,
                                                    const _Float16* __restrict__ Wt,
                                                    const float* __restrict__ bias,
                                                    _Float16* __restrict__ XWh) {
    __shared__ __align__(16) _Float16 Ah[128][32];
    __shared__ __align__(16) _Float16 Bh[128][32];

    const int tid  = threadIdx.x;
    const int wv   = tid >> 6;
    const int lane = tid & 63;
    const int bn   = blockIdx.x & 3;
    const int bm   = blockIdx.x >> 2;
    const int m0   = bm * 128;
    const int n0   = bn * 128;

    const int mbase = (wv >> 1) * 64;
    const int nbase = (wv & 1) * 64;
    const int fr    = lane & 15;
    const int fq    = lane >> 4;

    f32x4 acc[4][4];
    #pragma unroll
    for (int i = 0; i < 4; ++i)
        #pragma unroll
        for (int j = 0; j < 4; ++j)
            acc[i][j] = (f32x4){0.f, 0.f, 0.f, 0.f};

    for (int kc = 0; kc < DIN / 32; ++kc) {
        const int k0 = kc * 32;
#if __has_builtin(__builtin_amdgcn_global_load_lds)
        #pragma unroll
        for (int q = 0; q < 2; ++q) {
            const int rb = wv * 2 + q;
            const int gr = (rb * 16) + (lane >> 2);
            const int gc = (lane & 3) * 8;
            const _Float16* ga = Xh + (size_t)(m0 + gr) * DIN + k0 + gc;
            const _Float16* gb = Wt + (size_t)(n0 + gr) * DIN + k0 + gc;
            __builtin_amdgcn_global_load_lds(
                (const __attribute__((address_space(1))) void*)ga,
                (__attribute__((address_space(3))) void*)&Ah[rb * 16][0], 16, 0, 0);
            __builtin_amdgcn_global_load_lds(
                (const __attribute__((address_space(1))) void*)gb,
                (__attribute__((address_space(3))) void*)&Bh[rb * 16][0], 16, 0, 0);
        }
#else
        #pragma unroll
        for (int q = 0; q < 2; ++q) {
            const int h0 = (q * 256 + tid) * 8;
            const int row = h0 >> 5, col = h0 & 31;
            *((uint4*)Ah + (q * 256 + tid)) =
                *(const uint4*)(Xh + (size_t)(m0 + row) * DIN + k0 + col);
            *((uint4*)Bh + (q * 256 + tid)) =
                *(const uint4*)(Wt + (size_t)(n0 + row) * DIN + k0 + col);
        }
#endif
        __syncthreads();

        f16x8 af[4], bf[4];
        #pragma unroll
        for (int mt = 0; mt < 4; ++mt)
            af[mt] = *(const f16x8*)&Ah[mbase + mt * 16 + fr][fq * 8];
        #pragma unroll
        for (int nt = 0; nt < 4; ++nt)
            bf[nt] = *(const f16x8*)&Bh[nbase + nt * 16 + fr][fq * 8];
        #pragma unroll
        for (int mt = 0; mt < 4; ++mt)
            #pragma unroll
            for (int nt = 0; nt < 4; ++nt)
                acc[mt][nt] = __builtin_amdgcn_mfma_f32_16x16x32_f16(
                    af[mt], bf[nt], acc[mt][nt], 0, 0, 0);
        __syncthreads();
    }

    #pragma unroll
    for (int nt = 0; nt < 4; ++nt) {
        const int col = n0 + nbase + nt * 16 + fr;
        const float bvl = bias[col];
        #pragma unroll
        for (int mt = 0; mt < 4; ++mt) {
            #pragma unroll
            for (int r = 0; r < 4; ++r) {
                const int row = m0 + mbase + mt * 16 + fq * 4 + r;
                XWh[(size_t)row * DH + col] = (_Float16)(acc[mt][nt][r] + bvl);
            }
        }
    }
}

// ---------------------------------------------------------------------------
// K1d: permute XWh[row=b*T+t][col] -> XWp in scan-fragment order:
//   XWp[(((g*T + t)*4 + wv)*64 + lane)*32 + v],  v = s*4 + r,
//   where b = 16g + 4*(lane>>4) + r, col = 128wv + 16s + (lane&15).
// Scan then loads 4 coalesced uint4 per thread per step.
// ---------------------------------------------------------------------------
__global__ __launch_bounds__(256) void permute_xw(const _Float16* __restrict__ XWh,
                                                  _Float16* __restrict__ XWp) {
    __shared__ unsigned short Ls[16][520];   // 16 rows x 512 cols (+8 pad)
    const int bt = blockIdx.x;               // g*1024 + t
    const int g  = bt >> 10;
    const int t  = bt & 1023;
    const int i  = threadIdx.x;

    // stage: 16 rows (batches) of this timestep, coalesced
    {
        const int bq = i >> 4, seg = i & 15;
        const uint4* src = (const uint4*)(XWh +
            ((size_t)(16 * g + bq) * TSTEPS + t) * DH + seg * 32);
        uint4 q0 = src[0], q1 = src[1], q2 = src[2], q3 = src[3];
        uint4* dst = (uint4*)&Ls[bq][seg * 32];
        dst[0] = q0; dst[1] = q1; dst[2] = q2; dst[3] = q3;
    }
    __syncthreads();

    // gather into fragment order, store coalesced
    {
        const int wv = i >> 6, lane = i & 63;
        const int fr = lane & 15, fq = lane >> 4;
        unsigned int ow[16];
        #pragma unroll
        for (int p = 0; p < 16; ++p) {       // word p covers v=2p (r even) and v=2p+1
            const int s  = p >> 1;
            const int r0 = (2 * p) & 3;
            unsigned int a = Ls[4 * fq + r0][128 * wv + 16 * s + fr];
            unsigned int b = Ls[4 * fq + r0 + 1][128 * wv + 16 * s + fr];
            ow[p] = a | (b << 16);
        }
        uint4* dst = (uint4*)(XWp + (((size_t)bt * 4 + wv) * 64 + lane) * 32);
        dst[0] = (uint4){ow[0],  ow[1],  ow[2],  ow[3]};
        dst[1] = (uint4){ow[4],  ow[5],  ow[6],  ow[7]};
        dst[2] = (uint4){ow[8],  ow[9],  ow[10], ow[11]};
        dst[3] = (uint4){ow[12], ow[13], ow[14], ow[15]};
    }
}

// ---------------------------------------------------------------------------
// K2: MFMA scan v6. 4 wgs x 256 thr (4 waves, 1 wave/SIMD -> 512 regs/wave).
// Wave wv owns cols [128wv, 128wv+128): slices s0..s5 reg-resident B-frags,
// s6 LDS-resident, s7 streamed from L2 (window-4). H dbuf in LDS, swizzled,
// one barrier/step. Fragment layouts as validated in gemm_xw_mfma:
//   A: lane(fr,fq): H[m=fr][k=32c+8fq+j]
//   B: lane(fr,fq): Wr[k=32c+8fq+j][col=base+fr]     (WrT[col][k] rows)
//   C: lane(fr,fq): D[m=4fq+r][col=base+16s+fr]
// ---------------------------------------------------------------------------
__global__ __launch_bounds__(256, 1) void rnn_scan6(const _Float16* __restrict__ XWp,
                                                    const _Float16* __restrict__ WrT,
                                                    float* __restrict__ Hout) {
    extern __shared__ unsigned int lds[];
    unsigned int* wrl = lds;                   // [4 waves][4096 words]
    unsigned int* hb  = lds + 4 * SLICE_W;     // [2][4096 words]

    const int tid  = threadIdx.x;
    const int wv   = tid >> 6;
    const int lane = tid & 63;
    const int fr   = lane & 15;
    const int fq   = lane >> 4;
    const int g    = blockIdx.x;               // batch group: batches [16g,16g+16)

    // ---- one-time: B-frags for slices 0..5 -> registers (384 words, V+A) ----
    f16x8 breg[6][16];
    #pragma unroll
    for (int s = 0; s < 6; ++s) {
        const _Float16* pb = WrT + (size_t)(wv * 128 + s * 16 + fr) * DIN + fq * 8;
        #pragma unroll
        for (int c = 0; c < 16; ++c)
            breg[s][c] = *(const f16x8*)(pb + c * 32);
    }
    // ---- one-time: slice 6 -> LDS (each lane writes its own read addresses) ----
    {
        const _Float16* pb = WrT + (size_t)(wv * 128 + 96 + fr) * DIN + fq * 8;
        unsigned int* base = wrl + wv * SLICE_W + fr * 256;
        #pragma unroll
        for (int c = 0; c < 16; ++c)
            *(uint4*)(base + swz(fr, 16 * c + 4 * fq)) = *(const uint4*)(pb + c * 32);
    }
    // streamed slice 7 base (L2-resident after first step)
    const _Float16* p7 = WrT + (size_t)(wv * 128 + 112 + fr) * DIN + fq * 8;

    // zero both H buffers (h0 = 0)
    for (int i = tid; i < 2 * HBUF_W; i += 256) hb[i] = 0u;
    __syncthreads();

    // xw base for this thread; per-step stride = 4*64*32 = 8192 halves
    const _Float16* xwb = XWp + ((size_t)(g * TSTEPS * 4 + wv) * 64 + lane) * 32;
    f16x8 xq[4];
    {
        const uint4* p = (const uint4*)xwb;
        xq[0] = __builtin_bit_cast(f16x8, p[0]);
        xq[1] = __builtin_bit_cast(f16x8, p[1]);
        xq[2] = __builtin_bit_cast(f16x8, p[2]);
        xq[3] = __builtin_bit_cast(f16x8, p[3]);
    }

    int cur = 0;
    #pragma unroll 1
    for (int t = 0; t < TSTEPS; ++t) {
        const unsigned int* ha = hb + cur * HBUF_W;
        const unsigned int* b6b = wrl + wv * SLICE_W;

        // bulk-issue stream window (4 in flight; consumed >=4 iters later)
        f16x8 sreg[4];
        #pragma unroll
        for (int c0 = 0; c0 < 4; ++c0)
            sreg[c0] = *(const f16x8*)(p7 + c0 * 32);

        f32x4 cc[8];
        #pragma unroll
        for (int s = 0; s < 8; ++s) cc[s] = (f32x4){0.f, 0.f, 0.f, 0.f};

        #pragma unroll
        for (int c = 0; c < 16; ++c) {
            const int off = swz(fr, 16 * c + 4 * fq);
            f16x8 af = __builtin_bit_cast(f16x8, *(const uint4*)(ha + fr * 256 + off));
            f16x8 b6 = __builtin_bit_cast(f16x8, *(const uint4*)(b6b + fr * 256 + off));
            cc[0] = __builtin_amdgcn_mfma_f32_16x16x32_f16(af, breg[0][c], cc[0], 0, 0, 0);
            cc[1] = __builtin_amdgcn_mfma_f32_16x16x32_f16(af, breg[1][c], cc[1], 0, 0, 0);
            cc[2] = __builtin_amdgcn_mfma_f32_16x16x32_f16(af, breg[2][c], cc[2], 0, 0, 0);
            cc[3] = __builtin_amdgcn_mfma_f32_16x16x32_f16(af, breg[3][c], cc[3], 0, 0, 0);
            cc[4] = __builtin_amdgcn_mfma_f32_16x16x32_f16(af, breg[4][c], cc[4], 0, 0, 0);
            cc[5] = __builtin_amdgcn_mfma_f32_16x16x32_f16(af, breg[5][c], cc[5], 0, 0, 0);
            cc[6] = __builtin_amdgcn_mfma_f32_16x16x32_f16(af, b6,         cc[6], 0, 0, 0);
            f16x8 s7 = sreg[c & 3];
            if (c + 4 < 16)
                sreg[c & 3] = *(const f16x8*)(p7 + (c + 4) * 32);
            cc[7] = __builtin_amdgcn_mfma_f32_16x16x32_f16(af, s7,         cc[7], 0, 0, 0);
        }

        // prefetch next step's xw (HBM latency hidden across epilogue+barrier)
        f16x8 xn[4];
        {
            const size_t tn = (t + 1 < TSTEPS) ? (size_t)(t + 1) : (size_t)t;
            const uint4* p = (const uint4*)(xwb + tn * 8192);
            xn[0] = __builtin_bit_cast(f16x8, p[0]);
            xn[1] = __builtin_bit_cast(f16x8, p[1]);
            xn[2] = __builtin_bit_cast(f16x8, p[2]);
            xn[3] = __builtin_bit_cast(f16x8, p[3]);
        }

        // epilogue: h = tanh(cc + xw) -> fp16 into other H buffer (swizzled)
        unsigned short* hn = (unsigned short*)(hb + (cur ^ 1) * HBUF_W);
        #pragma unroll
        for (int s = 0; s < 8; ++s) {
            #pragma unroll
            for (int r = 0; r < 4; ++r) {
                const int v = s * 4 + r;
                const float xvv = (float)xq[v >> 3][v & 7];
                const float h = ftanh(cc[s][r] + xvv);
                const int m = 4 * fq + r;
                const int w = (64 * wv + 8 * s + (fr >> 1)) ^ ((m & 7) << 2);
                hn[(m * 256 + w) * 2 + (fr & 1)] = f2h_bits(h);
            }
        }
        __syncthreads();
        cur ^= 1;
        xq[0] = xn[0]; xq[1] = xn[1]; xq[2] = xn[2]; xq[3] = xn[3];
    }

    // final H (buffer `cur` after even number of flips) -> fp32 output
    {
        const unsigned int* hf = hb + cur * HBUF_W;
        const int m   = tid >> 4;
        const int seg = tid & 15;
        #pragma unroll
        for (int k = 0; k < 4; ++k) {
            const int o = seg * 16 + k * 4;             // 4-word group, swizzle-safe
            uint4 q = *(const uint4*)(hf + m * 256 + (o ^ ((m & 7) << 2)));
            f16x8 v = __builtin_bit_cast(f16x8, q);
            float4 o0 = { (float)v[0], (float)v[1], (float)v[2], (float)v[3] };
            float4 o1 = { (float)v[4], (float)v[5], (float)v[6], (float)v[7] };
            float* dst = &Hout[(size_t)(g * MB + m) * DH + seg * 32 + k * 8];
            *(float4*)dst       = o0;
            *(float4*)(dst + 4) = o1;
        }
    }
}

// ---------------------------------------------------------------------------
// launch
// ---------------------------------------------------------------------------
extern "C" void kernel_launch(void* const* d_in, const int* in_sizes, int n_in,
                              void* d_out, int out_size, void* d_ws, size_t ws_size,
                              hipStream_t stream) {
    const float* x  = (const float*)d_in[0];
    const float* W  = (const float*)d_in[1];
    const float* Wr = (const float*)d_in[2];
    const float* bv = (const float*)d_in[3];
    float* out = (float*)d_out;

    const size_t XWH_BYTES = (size_t)MDIM * DH * sizeof(_Float16);   // 67.1 MB
    const size_t XH_BYTES  = (size_t)MDIM * DIN * sizeof(_Float16);  // 67.1 MB
    const size_t WT_BYTES  = (size_t)DIN * DH * sizeof(_Float16);    //  0.5 MB
    if (ws_size < XWH_BYTES + XH_BYTES + 2 * WT_BYTES) return;

    _Float16* xwh = (_Float16*)d_ws;
    _Float16* xh  = (_Float16*)((char*)d_ws + XWH_BYTES);            // reused as XWp
    _Float16* wt  = (_Float16*)((char*)d_ws + XWH_BYTES + XH_BYTES);
    _Float16* wrt = (_Float16*)((char*)d_ws + XWH_BYTES + XH_BYTES + WT_BYTES);
    _Float16* xwp = xh;   // Xh dead after gemm; permute writes into its space

    hipFuncSetAttribute((const void*)rnn_scan6,
                        hipFuncAttributeMaxDynamicSharedMemorySize, K2_LDS_BYTES);

    convert_x<<<dim3(2048), dim3(256), 0, stream>>>(x, xh, MDIM * DIN / 8);
    transpose_w<<<dim3(64), dim3(256), 0, stream>>>(W, wt);
    transpose_w<<<dim3(64), dim3(256), 0, stream>>>(Wr, wrt);
    gemm_xw_mfma<<<dim3((MDIM / 128) * (DH / 128)), dim3(256), 0, stream>>>(
        xh, wt, bv, xwh);
    permute_xw<<<dim3(4 * TSTEPS), dim3(256), 0, stream>>>(xwh, xwp);
    rnn_scan6<<<dim3(BATCH / MB), dim3(256), K2_LDS_BYTES, stream>>>(xwp, wrt, out);
}